// Round 2
// baseline (12783.407 us; speedup 1.0000x reference)
//
#include <hip/hip_runtime.h>

// Problem: B=32, T=128, I=H=O=512, L=2, bidirectional GRU + FC head.
// ws layout (floats):
//   proj : [2][128][32][1536] = 12,582,912
//   seq  : [2][128][32][512]  =  4,194,304
//   flags: 2 layers x 256 ints (in float-space, 512 elems)
#define PROJ_ELEMS 12582912
#define SEQ_ELEMS  4194304

// ---------------- proj GEMM: [8192 x 1536] = src @ [Wxh | Wxr] + bias ----------------
// grid (12, 64), block 256. 128x128 tile, 8x8 per-thread register tile. (unchanged R1)
__global__ __launch_bounds__(256)
void proj_kernel(const float* __restrict__ src,
                 const float* __restrict__ Wxh, const float* __restrict__ bxh,
                 const float* __restrict__ Wxr, const float* __restrict__ bxr,
                 float* __restrict__ proj, int layer)
{
    __shared__ float As[32][137];   // [k][row] transposed A tile
    __shared__ float Ws[32][132];   // [k][col]
    const int tid  = threadIdx.x;
    const int col0 = blockIdx.x * 128;
    const int row0 = blockIdx.y * 128;
    const int d    = row0 >> 12;              // rows 0..4095 = dir0, 4096..8191 = dir1
    const int ld   = layer * 2 + d;
    const int tx = tid & 15, ty = tid >> 4;

    const bool is_xr = (col0 >= 1024);
    const float* Wbase = is_xr ? (Wxr + (size_t)ld * 512 * 512 + (col0 - 1024))
                               : (Wxh + (size_t)ld * 512 * 1024 + col0);
    const int wstride = is_xr ? 512 : 1024;
    const float* bias = is_xr ? (bxr + ld * 512 + (col0 - 1024))
                              : (bxh + ld * 1024 + col0);

    float acc[8][8];
    #pragma unroll
    for (int i = 0; i < 8; i++)
        #pragma unroll
        for (int j = 0; j < 8; j++) acc[i][j] = 0.f;

    for (int k0 = 0; k0 < 512; k0 += 32) {
        #pragma unroll
        for (int v = 0; v < 4; v++) {
            int idx = tid + v * 256;
            int r   = idx >> 3;
            int c4  = (idx & 7) << 2;
            int gm  = row0 + r;
            int rr  = gm & 4095;
            int tt  = rr >> 5, bb = rr & 31;
            const float* p;
            if (layer == 0) {
                int ts = (gm >= 4096) ? (127 - tt) : tt;  // dir1 reads reversed time
                p = src + ((size_t)bb * 128 + ts) * 512 + (k0 + c4);
            } else {
                p = src + (((size_t)(gm >> 12) * 128 + tt) * 32 + bb) * 512 + (k0 + c4);
            }
            float4 vv = *(const float4*)p;
            As[c4 + 0][r] = vv.x; As[c4 + 1][r] = vv.y;
            As[c4 + 2][r] = vv.z; As[c4 + 3][r] = vv.w;
        }
        #pragma unroll
        for (int v = 0; v < 4; v++) {
            int idx = tid + v * 256;
            int kr  = idx >> 5;
            int c4  = (idx & 31) << 2;
            *(float4*)&Ws[kr][c4] = *(const float4*)(Wbase + (size_t)(k0 + kr) * wstride + c4);
        }
        __syncthreads();
        #pragma unroll
        for (int kk = 0; kk < 32; kk++) {
            float a[8], w[8];
            *(float4*)&a[0] = *(const float4*)&As[kk][ty * 8];
            *(float4*)&a[4] = *(const float4*)&As[kk][ty * 8 + 4];
            *(float4*)&w[0] = *(const float4*)&Ws[kk][tx * 8];
            *(float4*)&w[4] = *(const float4*)&Ws[kk][tx * 8 + 4];
            #pragma unroll
            for (int i = 0; i < 8; i++)
                #pragma unroll
                for (int j = 0; j < 8; j++)
                    acc[i][j] += a[i] * w[j];
        }
        __syncthreads();
    }
    #pragma unroll
    for (int i = 0; i < 8; i++) {
        int gm = row0 + ty * 8 + i;
        float* dst = proj + (size_t)gm * 1536 + col0 + tx * 8;
        #pragma unroll
        for (int j = 0; j < 8; j++)
            dst[j] = acc[i][j] + bias[tx * 8 + j];
    }
}

// ---------------- persistent recurrence: one kernel per layer ----------------
// grid 256 = dir(2) x jblock(128, 4 cols each), block 256 = 4 waves.
// Weights in VGPRs: thread (bg, ksub, jl) holds W[k in chunk(ksub)][j0+jl] for 3 gates.
// h in LDS (64KB), re-staged from global seq[t] after a distributed flag barrier.
__global__ __launch_bounds__(256)
void recur_kernel(const float* __restrict__ proj, float* __restrict__ seq,
                  const float* __restrict__ Whh, const float* __restrict__ bhh,
                  const float* __restrict__ Whr, const float* __restrict__ bhr,
                  int* __restrict__ flags, int layer)
{
    __shared__ __align__(16) float hs[32 * 512];     // h_prev [b][k], flat
    __shared__ float fin[32 * 4 * 3];                // [b][jl][gate] reduced pre-activations
    __shared__ float bz_s[4], br_s[4], bg_s[4];

    const int blk = blockIdx.x;
    const int d   = blk >> 7;          // direction
    const int jb  = blk & 127;         // j-block within dir
    const int j0  = jb * 4;
    const int ld  = layer * 2 + d;
    const int tid = threadIdx.x;
    const int bg  = tid >> 6;          // wave id = batch group (8 b each)
    const int lane = tid & 63;
    const int ksub = lane >> 2;        // 16 k-chunks
    const int jl   = lane & 3;
    const int j    = j0 + jl;

    int* flg = flags + layer * 256;

    if (tid < 4) {
        bz_s[tid] = bhh[ld * 1024 + j0 + tid];
        br_s[tid] = bhh[ld * 1024 + 512 + j0 + tid];
        bg_s[tid] = bhr[ld * 512 + j0 + tid];
    }

    // ---- load weight slice into registers: k = 4*ksub + 64*m + i, m=0..7, i=0..3 ----
    float wz[32], wr[32], wg[32];
    {
        const float* WhhL = Whh + (size_t)ld * 512 * 1024;
        const float* WhrL = Whr + (size_t)ld * 512 * 512;
        #pragma unroll
        for (int m = 0; m < 8; m++) {
            int kbase = 4 * ksub + 64 * m;
            #pragma unroll
            for (int i = 0; i < 4; i++) {
                wz[4 * m + i] = WhhL[(size_t)(kbase + i) * 1024 + j];
                wr[4 * m + i] = WhhL[(size_t)(kbase + i) * 1024 + 512 + j];
                wg[4 * m + i] = WhrL[(size_t)(kbase + i) * 512 + j];
            }
        }
    }

    // ---- zero initial h ----
    #pragma unroll
    for (int v = 0; v < 16; v++) {
        int id = tid + v * 256;
        *(float4*)&hs[id * 4] = make_float4(0.f, 0.f, 0.f, 0.f);
    }
    __syncthreads();

    for (int t = 0; t < 128; t++) {
        // ---- partial GEMV: each thread, 8 batches x its 32-k chunk x 3 gates ----
        float az[8], ar[8], ag[8];
        #pragma unroll
        for (int bo = 0; bo < 8; bo++) { az[bo] = 0.f; ar[bo] = 0.f; ag[bo] = 0.f; }
        #pragma unroll
        for (int bo = 0; bo < 8; bo++) {
            const float* hrow = hs + (bg * 8 + bo) * 512 + 4 * ksub;
            #pragma unroll
            for (int m = 0; m < 8; m++) {
                float4 hv = *(const float4*)(hrow + 64 * m);  // 2-way bank alias: free
                az[bo] += hv.x * wz[4*m+0] + hv.y * wz[4*m+1] + hv.z * wz[4*m+2] + hv.w * wz[4*m+3];
                ar[bo] += hv.x * wr[4*m+0] + hv.y * wr[4*m+1] + hv.z * wr[4*m+2] + hv.w * wr[4*m+3];
                ag[bo] += hv.x * wg[4*m+0] + hv.y * wg[4*m+1] + hv.z * wg[4*m+2] + hv.w * wg[4*m+3];
            }
        }
        // ---- butterfly reduce across ksub (lane bits 2..5) ----
        #pragma unroll
        for (int mask = 4; mask <= 32; mask <<= 1) {
            #pragma unroll
            for (int bo = 0; bo < 8; bo++) {
                az[bo] += __shfl_xor(az[bo], mask, 64);
                ar[bo] += __shfl_xor(ar[bo], mask, 64);
                ag[bo] += __shfl_xor(ag[bo], mask, 64);
            }
        }
        if (ksub == 0) {
            #pragma unroll
            for (int bo = 0; bo < 8; bo++) {
                int b = bg * 8 + bo;
                fin[(b * 4 + jl) * 3 + 0] = az[bo];
                fin[(b * 4 + jl) * 3 + 1] = ar[bo];
                fin[(b * 4 + jl) * 3 + 2] = ag[bo];
            }
        }
        __syncthreads();
        // ---- finalize: 128 threads = (b, jl) ----
        if (tid < 128) {
            int b = tid >> 2, q = tid & 3;
            size_t pbase = ((size_t)(d * 128 + t) * 32 + b) * 1536;
            float sz = fin[(b * 4 + q) * 3 + 0] + proj[pbase + j0 + q]        + bz_s[q];
            float sr = fin[(b * 4 + q) * 3 + 1] + proj[pbase + 512 + j0 + q]  + br_s[q];
            float sg = fin[(b * 4 + q) * 3 + 2];
            float z = 1.f / (1.f + expf(-sz));
            float r = 1.f / (1.f + expf(-sr));
            float g = tanhf((sg + bg_s[q]) * r + proj[pbase + 1024 + j0 + q]);
            float hv = hs[b * 512 + j0 + q];
            float hn = z * hv + (1.f - z) * g;
            seq[((size_t)(d * 128 + t) * 32 + b) * 512 + j0 + q] = hn;
        }
        if (t == 127) break;
        // ---- release: make h writes agent-visible, then post flag ----
        __threadfence();
        __syncthreads();
        if (tid == 0)
            __hip_atomic_store(&flg[d * 128 + jb], t + 1, __ATOMIC_RELEASE, __HIP_MEMORY_SCOPE_AGENT);
        // ---- wait for all 128 blocks of this dir ----
        if (tid < 64) {
            int i0 = d * 128 + tid, i1 = i0 + 64;
            while (__hip_atomic_load(&flg[i0], __ATOMIC_RELAXED, __HIP_MEMORY_SCOPE_AGENT) <= t ||
                   __hip_atomic_load(&flg[i1], __ATOMIC_RELAXED, __HIP_MEMORY_SCOPE_AGENT) <= t) {
                __builtin_amdgcn_s_sleep(2);
            }
        }
        __syncthreads();
        __threadfence();   // acquire: invalidate stale cache before reading peers' h
        // ---- stage full h(t) -> LDS ----
        const float* hsrc = seq + (size_t)(d * 128 + t) * 32 * 512;
        #pragma unroll
        for (int v = 0; v < 16; v++) {
            int id = tid + v * 256;
            *(float4*)&hs[id * 4] = *(const float4*)(hsrc + id * 4);
        }
        __syncthreads();
    }
}

// ---------------- final FC ----------------
__global__ __launch_bounds__(256)
void fc_kernel(const float* __restrict__ seq, const float* __restrict__ Wfc,
               const float* __restrict__ bfc, float* __restrict__ out)
{
    int idx = blockIdx.x * 256 + threadIdx.x;   // 0..16383
    int b = idx >> 9, o = idx & 511;
    const float* catf = seq + ((size_t)(0 * 128 + 127) * 32 + b) * 512;  // fwd, t=127
    const float* catr = seq + ((size_t)(1 * 128 + 0) * 32 + b) * 512;    // rev, t=0
    float acc = bfc[o];
    #pragma unroll 8
    for (int k = 0; k < 512; k++) acc += catf[k] * Wfc[(size_t)k * 512 + o];
    #pragma unroll 8
    for (int k = 0; k < 512; k++) acc += catr[k] * Wfc[(size_t)(512 + k) * 512 + o];
    out[(size_t)b * 512 + o] = acc;
}

extern "C" void kernel_launch(void* const* d_in, const int* in_sizes, int n_in,
                              void* d_out, int out_size, void* d_ws, size_t ws_size,
                              hipStream_t stream) {
    (void)in_sizes; (void)n_in; (void)out_size; (void)ws_size;
    const float* x   = (const float*)d_in[0];
    const float* Wxh = (const float*)d_in[1];
    const float* bxh = (const float*)d_in[2];
    const float* Whh = (const float*)d_in[3];
    const float* bhh = (const float*)d_in[4];
    const float* Wxr = (const float*)d_in[5];
    const float* bxr = (const float*)d_in[6];
    const float* Whr = (const float*)d_in[7];
    const float* bhr = (const float*)d_in[8];
    const float* Wfc = (const float*)d_in[9];
    const float* bfc = (const float*)d_in[10];
    float* out  = (float*)d_out;
    float* ws   = (float*)d_ws;
    float* proj = ws;
    float* seq  = ws + PROJ_ELEMS;
    int*   flags = (int*)(ws + PROJ_ELEMS + SEQ_ELEMS);

    hipMemsetAsync(flags, 0, 2 * 256 * sizeof(int), stream);

    dim3 pgrid(12, 64);
    proj_kernel<<<pgrid, 256, 0, stream>>>(x, Wxh, bxh, Wxr, bxr, proj, 0);
    recur_kernel<<<256, 256, 0, stream>>>(proj, seq, Whh, bhh, Whr, bhr, flags, 0);
    proj_kernel<<<pgrid, 256, 0, stream>>>(seq, Wxh, bxh, Wxr, bxr, proj, 1);
    recur_kernel<<<256, 256, 0, stream>>>(proj, seq, Whh, bhh, Whr, bhr, flags, 1);
    fc_kernel<<<64, 256, 0, stream>>>(seq, Wfc, bfc, out);
}

// Round 3
// 2712.713 us; speedup vs baseline: 4.7124x; 4.7124x over previous
//
#include <hip/hip_runtime.h>
#include <hip/hip_bf16.h>

// Problem: B=32, T=128, I=H=O=512, L=2, bidirectional GRU + FC head.
// ws layout (bytes):
//   proj (bf16): [2][128][32][1536]            = 12,582,912 elems * 2B = 25.17 MB
//   seq  (fp32): [2][128][32][512]             =  4,194,304 elems * 4B = 16.78 MB
//   slabs(fp32): [2l][2d][128jb][6144]         =  6,291,456 elems * 4B = 25.17 MB
// total 67.12 MB (== R1's proven footprint)
#define PROJ_ELEMS 12582912
#define SEQ_ELEMS  4194304
#define SLAB_PER_BLK 6144

// ---------------- proj GEMM: [8192 x 1536] = src @ [Wxh | Wxr] + bias -> bf16 ----------------
// grid (12, 64), block 256. 128x128 tile, 8x8 per-thread register tile.
__global__ __launch_bounds__(256)
void proj_kernel(const float* __restrict__ src,
                 const float* __restrict__ Wxh, const float* __restrict__ bxh,
                 const float* __restrict__ Wxr, const float* __restrict__ bxr,
                 __hip_bfloat16* __restrict__ proj, int layer)
{
    __shared__ float As[32][137];   // [k][row] transposed A tile
    __shared__ float Ws[32][132];   // [k][col]
    const int tid  = threadIdx.x;
    const int col0 = blockIdx.x * 128;
    const int row0 = blockIdx.y * 128;
    const int d    = row0 >> 12;              // rows 0..4095 = dir0, 4096..8191 = dir1
    const int ld   = layer * 2 + d;
    const int tx = tid & 15, ty = tid >> 4;

    const bool is_xr = (col0 >= 1024);
    const float* Wbase = is_xr ? (Wxr + (size_t)ld * 512 * 512 + (col0 - 1024))
                               : (Wxh + (size_t)ld * 512 * 1024 + col0);
    const int wstride = is_xr ? 512 : 1024;
    const float* bias = is_xr ? (bxr + ld * 512 + (col0 - 1024))
                              : (bxh + ld * 1024 + col0);

    float acc[8][8];
    #pragma unroll
    for (int i = 0; i < 8; i++)
        #pragma unroll
        for (int j = 0; j < 8; j++) acc[i][j] = 0.f;

    for (int k0 = 0; k0 < 512; k0 += 32) {
        #pragma unroll
        for (int v = 0; v < 4; v++) {
            int idx = tid + v * 256;
            int r   = idx >> 3;
            int c4  = (idx & 7) << 2;
            int gm  = row0 + r;
            int rr  = gm & 4095;
            int tt  = rr >> 5, bb = rr & 31;
            const float* p;
            if (layer == 0) {
                int ts = (gm >= 4096) ? (127 - tt) : tt;  // dir1 reads reversed time
                p = src + ((size_t)bb * 128 + ts) * 512 + (k0 + c4);
            } else {
                p = src + (((size_t)(gm >> 12) * 128 + tt) * 32 + bb) * 512 + (k0 + c4);
            }
            float4 vv = *(const float4*)p;
            As[c4 + 0][r] = vv.x; As[c4 + 1][r] = vv.y;
            As[c4 + 2][r] = vv.z; As[c4 + 3][r] = vv.w;
        }
        #pragma unroll
        for (int v = 0; v < 4; v++) {
            int idx = tid + v * 256;
            int kr  = idx >> 5;
            int c4  = (idx & 31) << 2;
            *(float4*)&Ws[kr][c4] = *(const float4*)(Wbase + (size_t)(k0 + kr) * wstride + c4);
        }
        __syncthreads();
        #pragma unroll
        for (int kk = 0; kk < 32; kk++) {
            float a[8], w[8];
            *(float4*)&a[0] = *(const float4*)&As[kk][ty * 8];
            *(float4*)&a[4] = *(const float4*)&As[kk][ty * 8 + 4];
            *(float4*)&w[0] = *(const float4*)&Ws[kk][tx * 8];
            *(float4*)&w[4] = *(const float4*)&Ws[kk][tx * 8 + 4];
            #pragma unroll
            for (int i = 0; i < 8; i++)
                #pragma unroll
                for (int j = 0; j < 8; j++)
                    acc[i][j] += a[i] * w[j];
        }
        __syncthreads();
    }
    #pragma unroll
    for (int i = 0; i < 8; i++) {
        int gm = row0 + ty * 8 + i;
        __hip_bfloat16* dst = proj + (size_t)gm * 1536 + col0 + tx * 8;
        #pragma unroll
        for (int j = 0; j < 8; j++)
            dst[j] = __float2bfloat16(acc[i][j] + bias[tx * 8 + j]);
    }
}

// ---------------- weight repack: per-(ld,jb) contiguous slab ----------------
// slab[(ld*128+jb)][idx], idx = (g*4+cg)*12 + e*4 + ki ; k = g*4+ki, j = jb*4+cg
// e: 0 = Whh z-col j, 1 = Whh r-col 512+j, 2 = Whr g-col j.
__global__ __launch_bounds__(256)
void repack_kernel(const float* __restrict__ Whh, const float* __restrict__ Whr,
                   float* __restrict__ slabs)
{
    const int blk = blockIdx.x;           // 0..511 = ld*128 + jb
    const int ld = blk >> 7, jb = blk & 127;
    const float* WhhL = Whh + (size_t)ld * 512 * 1024;
    const float* WhrL = Whr + (size_t)ld * 512 * 512;
    float* out = slabs + (size_t)blk * SLAB_PER_BLK;
    for (int u = 0; u < 24; u++) {
        int idx = threadIdx.x + u * 256;  // 0..6143
        int rec = idx / 12, r3 = idx % 12;
        int g = rec >> 2, cg = rec & 3;
        int e = r3 >> 2, ki = r3 & 3;
        int k = g * 4 + ki, j = jb * 4 + cg;
        float v;
        if (e == 0)      v = WhhL[(size_t)k * 1024 + j];
        else if (e == 1) v = WhhL[(size_t)k * 1024 + 512 + j];
        else             v = WhrL[(size_t)k * 512 + j];
        out[idx] = v;
    }
}

// ---------------- GRU step: both dirs, one timestep ----------------
// grid 256 = d*128 + jb (4 j-cols each), block 256 = (b = tid>>3, kh = bit2, cg = tid&3)
// Each thread: full 256-k strip of the GEMV for (b, j), weights streamed from its slab.
__global__ __launch_bounds__(256)
void step_kernel(const __hip_bfloat16* __restrict__ proj, float* __restrict__ seq,
                 const float* __restrict__ slabs,
                 const float* __restrict__ bhh, const float* __restrict__ bhr,
                 int layer, int t)
{
    __shared__ __align__(16) float hs[32 * 512];  // h swizzled: [b][(g^(b&7))*4 + ki]
    const int tid = threadIdx.x;
    const int d   = blockIdx.x >> 7;
    const int jb  = blockIdx.x & 127;
    const int ld  = layer * 2 + d;
    const int cg  = tid & 3;
    const int kh  = (tid >> 2) & 1;
    const int b   = tid >> 3;
    const int j   = jb * 4 + cg;
    const int sb  = b & 7;

    float az = 0.f, ar = 0.f, ag = 0.f;
    float hv_self = 0.f;

    if (t > 0) {
        // stage h(t-1) -> LDS with XOR-on-float4-slot swizzle (kills 8-way b-conflicts)
        const float* hsrc = seq + ((size_t)(d * 128 + (t - 1)) * 32) * 512;
        #pragma unroll
        for (int v = 0; v < 16; v++) {
            int id = tid + v * 256;           // float4 id 0..4095
            int bb = id >> 7, g = id & 127;
            float4 hv = *(const float4*)(hsrc + (size_t)id * 4);
            *(float4*)&hs[bb * 512 + ((g ^ (bb & 7)) << 2)] = hv;
        }
        __syncthreads();

        const float4* wrec = (const float4*)slabs + (size_t)(ld * 128 + jb) * 1536;
        #pragma unroll 4
        for (int gg = 0; gg < 64; gg++) {
            int g = kh * 64 + gg;
            float4 h4 = *(const float4*)&hs[b * 512 + ((g ^ sb) << 2)];
            const float4* wp = wrec + (size_t)(g * 4 + cg) * 3;
            float4 wz = wp[0], wr = wp[1], wg = wp[2];
            az += h4.x * wz.x + h4.y * wz.y + h4.z * wz.z + h4.w * wz.w;
            ar += h4.x * wr.x + h4.y * wr.y + h4.z * wr.z + h4.w * wr.w;
            ag += h4.x * wg.x + h4.y * wg.y + h4.z * wg.z + h4.w * wg.w;
        }
        // combine the two k-halves (lanes differ in bit 2)
        az += __shfl_xor(az, 4, 64);
        ar += __shfl_xor(ar, 4, 64);
        ag += __shfl_xor(ag, 4, 64);
        hv_self = hs[b * 512 + ((jb ^ sb) << 2) + cg];   // g_self = j>>2 = jb
    }

    const size_t pb = ((size_t)(d * 128 + t) * 32 + b) * 1536;
    float pz = __bfloat162float(proj[pb + j]);
    float pr = __bfloat162float(proj[pb + 512 + j]);
    float pg = __bfloat162float(proj[pb + 1024 + j]);
    float bz = bhh[ld * 1024 + j];
    float br = bhh[ld * 1024 + 512 + j];
    float bg = bhr[ld * 512 + j];
    float z  = 1.f / (1.f + __expf(-(az + pz + bz)));
    float r  = 1.f / (1.f + __expf(-(ar + pr + br)));
    float gt = tanhf((ag + bg) * r + pg);
    float hn = z * hv_self + (1.f - z) * gt;
    if (kh == 0)
        seq[((size_t)(d * 128 + t) * 32 + b) * 512 + j] = hn;
}

// ---------------- final FC ----------------
__global__ __launch_bounds__(256)
void fc_kernel(const float* __restrict__ seq, const float* __restrict__ Wfc,
               const float* __restrict__ bfc, float* __restrict__ out)
{
    int idx = blockIdx.x * 256 + threadIdx.x;   // 0..16383
    int b = idx >> 9, o = idx & 511;
    const float* catf = seq + ((size_t)(0 * 128 + 127) * 32 + b) * 512;  // fwd, t=127
    const float* catr = seq + ((size_t)(1 * 128 + 0) * 32 + b) * 512;    // rev, t=0
    float acc = bfc[o];
    #pragma unroll 8
    for (int k = 0; k < 512; k++) acc += catf[k] * Wfc[(size_t)k * 512 + o];
    #pragma unroll 8
    for (int k = 0; k < 512; k++) acc += catr[k] * Wfc[(size_t)(512 + k) * 512 + o];
    out[(size_t)b * 512 + o] = acc;
}

extern "C" void kernel_launch(void* const* d_in, const int* in_sizes, int n_in,
                              void* d_out, int out_size, void* d_ws, size_t ws_size,
                              hipStream_t stream) {
    (void)in_sizes; (void)n_in; (void)out_size; (void)ws_size;
    const float* x   = (const float*)d_in[0];
    const float* Wxh = (const float*)d_in[1];
    const float* bxh = (const float*)d_in[2];
    const float* Whh = (const float*)d_in[3];
    const float* bhh = (const float*)d_in[4];
    const float* Wxr = (const float*)d_in[5];
    const float* bxr = (const float*)d_in[6];
    const float* Whr = (const float*)d_in[7];
    const float* bhr = (const float*)d_in[8];
    const float* Wfc = (const float*)d_in[9];
    const float* bfc = (const float*)d_in[10];
    float* out = (float*)d_out;

    char* base = (char*)d_ws;
    __hip_bfloat16* proj = (__hip_bfloat16*)base;
    float* seq   = (float*)(base + (size_t)PROJ_ELEMS * 2);
    float* slabs = seq + SEQ_ELEMS;

    repack_kernel<<<512, 256, 0, stream>>>(Whh, Whr, slabs);

    dim3 pgrid(12, 64);
    proj_kernel<<<pgrid, 256, 0, stream>>>(x, Wxh, bxh, Wxr, bxr, proj, 0);
    for (int t = 0; t < 128; t++)
        step_kernel<<<256, 256, 0, stream>>>(proj, seq, slabs, bhh, bhr, 0, t);
    proj_kernel<<<pgrid, 256, 0, stream>>>(seq, Wxh, bxh, Wxr, bxr, proj, 1);
    for (int t = 0; t < 128; t++)
        step_kernel<<<256, 256, 0, stream>>>(proj, seq, slabs, bhh, bhr, 1, t);
    fc_kernel<<<64, 256, 0, stream>>>(seq, Wfc, bfc, out);
}